// Round 7
// baseline (1184.248 us; speedup 1.0000x reference)
//
#include <hip/hip_runtime.h>
#include <hip/hip_bf16.h>

#define N_PTS 8192
#define NSAMP 1024
#define NGRP  32

typedef __attribute__((ext_vector_type(8))) short bf16x8;   // MFMA A/B frag
typedef __attribute__((ext_vector_type(4))) float f32x4;    // MFMA C/D frag
typedef __attribute__((ext_vector_type(2))) float f32x2;    // packed fp32 pair

static __device__ inline unsigned short f2bf(float f) {
  __hip_bfloat16 h = __float2bfloat16(f);   // RTNE
  return __builtin_bit_cast(unsigned short, h);
}

// DPP max step: invalid lanes keep 'old' (=r), identity for max.
#define DPP_MAXSTEP(r, ctrl)                                                  \
  r = fmaxf(r, __int_as_float(__builtin_amdgcn_update_dpp(                    \
          __float_as_int(r), __float_as_int(r), (ctrl), 0xf, 0xf, false)))

static __device__ inline void load16(const float* __restrict__ bx, int t,
                                     float px[16], float py[16], float pz[16]) {
  const float4* src = (const float4*)(bx + t * 48);
  float4 v0 = src[0], v1 = src[1], v2 = src[2];
  float4 v3 = src[3], v4 = src[4], v5 = src[5];
  float4 v6 = src[6], v7 = src[7], v8 = src[8];
  float4 v9 = src[9], v10 = src[10], v11 = src[11];
  px[ 0]=v0.x; py[ 0]=v0.y; pz[ 0]=v0.z;
  px[ 1]=v0.w; py[ 1]=v1.x; pz[ 1]=v1.y;
  px[ 2]=v1.z; py[ 2]=v1.w; pz[ 2]=v2.x;
  px[ 3]=v2.y; py[ 3]=v2.z; pz[ 3]=v2.w;
  px[ 4]=v3.x; py[ 4]=v3.y; pz[ 4]=v3.z;
  px[ 5]=v3.w; py[ 5]=v4.x; pz[ 5]=v4.y;
  px[ 6]=v4.z; py[ 6]=v4.w; pz[ 6]=v5.x;
  px[ 7]=v5.y; py[ 7]=v5.z; pz[ 7]=v5.w;
  px[ 8]=v6.x; py[ 8]=v6.y; pz[ 8]=v6.z;
  px[ 9]=v6.w; py[ 9]=v7.x; pz[ 9]=v7.y;
  px[10]=v7.z; py[10]=v7.w; pz[10]=v8.x;
  px[11]=v8.y; py[11]=v8.z; pz[11]=v8.w;
  px[12]=v9.x; py[12]=v9.y; pz[12]=v9.z;
  px[13]=v9.w; py[13]=v10.x; pz[13]=v10.y;
  px[14]=v10.z; py[14]=v10.w; pz[14]=v11.x;
  px[15]=v11.y; py[15]=v11.z; pz[15]=v11.w;
}

// ---------------------------------------------------------------------------
// Kernel 1: farthest point sampling — R17.
// R12 structure (512thr x 16pts packed, 1 barrier) + COORDS-IN-PARTIALS:
// fps's output is coordinates, not indices — each wave's partial record now
// carries the winning point's (x,y,z), deleting the dependent centroid
// ds_read (~120-150cy) from the serial tail and the 96KB lds_p table.
// The per-lane coord-select chains run in the issue phase parallel to the
// DPP chain (R12/R13 proved issue slack hides them for free).
// Winner-selection logic (bv/DPP/ballot/lowest-lane/lowest-r/strict-> FINAL)
// unchanged -> bit-exact output.
//   d = fma(dz,dz, fma(dy,dy, dx*dx))          (bit-exact, DO NOT TOUCH)
// ---------------------------------------------------------------------------
__global__
__attribute__((amdgpu_flat_work_group_size(512, 512)))
__attribute__((amdgpu_waves_per_eu(2, 2)))
void fps_kernel(
    const float* __restrict__ xyz, float* __restrict__ out_sampled)
{
  #pragma clang fp contract(off)
  const int b = blockIdx.x;
  const int t = threadIdx.x;
  const float* bx = xyz + (size_t)b * N_PTS * 3;

  float px[16], py[16], pz[16];
  load16(bx, t, px, py, pz);

  f32x2 px2[8], py2[8], pz2[8], ds2[8];
  #pragma unroll
  for (int j = 0; j < 8; ++j) {
    px2[j] = (f32x2){px[2*j], px[2*j+1]};
    py2[j] = (f32x2){py[2*j], py[2*j+1]};
    pz2[j] = (f32x2){pz[2*j], pz[2*j+1]};
    ds2[j] = (f32x2){10000000000.0f, 10000000000.0f};
  }

  __shared__ float out_lds[NSAMP * 3];          // centroids, flushed at end
  __shared__ __align__(16) uint4 part[2][8];    // ping-pong {val, x, y, z}

  const int lane = t & 63;
  const int wv   = t >> 6;

  float cx = bx[0], cy = bx[1], cz = bx[2];  // initial centroid = point 0

  for (int it = 0; it < NSAMP; ++it) {
    if (t == 0) {
      out_lds[it * 3 + 0] = cx;
      out_lds[it * 3 + 1] = cy;
      out_lds[it * 3 + 2] = cz;
    }

    const f32x2 c2x = (f32x2){cx, cx};
    const f32x2 c2y = (f32x2){cy, cy};
    const f32x2 c2z = (f32x2){cz, cz};
    f32x2 bv2 = (f32x2){-1.0f, -1.0f};
    #pragma unroll
    for (int j = 0; j < 8; ++j) {
      f32x2 dx = px2[j] - c2x;
      f32x2 dy = py2[j] - c2y;
      f32x2 dz = pz2[j] - c2z;
      f32x2 d  = __builtin_elementwise_fma(
          dz, dz, __builtin_elementwise_fma(dy, dy, dx * dx));  // scan-fused
      f32x2 nd = __builtin_elementwise_min(ds2[j], d);
      ds2[j] = nd;
      bv2 = __builtin_elementwise_max(bv2, nd);
    }
    float bv = fmaxf(bv2.x, bv2.y);   // min/max reassociation is exact

    // per-lane winning point COORDS (same lowest-r predicate chain as the
    // old index chain -> same point selected; runs parallel to DPP below)
    float sx = px2[7].y, sy = py2[7].y, sz = pz2[7].y;   // r = 15
    #pragma unroll
    for (int r = 14; r >= 0; --r) {
      float dr = (r & 1) ? ds2[r >> 1].y : ds2[r >> 1].x;
      bool e = (dr == bv);
      float qx = (r & 1) ? px2[r >> 1].y : px2[r >> 1].x;
      float qy = (r & 1) ? py2[r >> 1].y : py2[r >> 1].x;
      float qz = (r & 1) ? pz2[r >> 1].y : pz2[r >> 1].x;
      sx = e ? qx : sx;
      sy = e ? qy : sy;
      sz = e ? qz : sz;
    }

    float rmax = bv;
    DPP_MAXSTEP(rmax, 0x111);  // row_shr:1
    DPP_MAXSTEP(rmax, 0x112);  // row_shr:2
    DPP_MAXSTEP(rmax, 0x114);  // row_shr:4
    DPP_MAXSTEP(rmax, 0x118);  // row_shr:8
    DPP_MAXSTEP(rmax, 0x142);  // row_bcast:15
    DPP_MAXSTEP(rmax, 0x143);  // row_bcast:31
    float vmax = __int_as_float(
        __builtin_amdgcn_readlane(__float_as_int(rmax), 63));

    unsigned long long m = __ballot(bv == vmax);
    int L = __ffsll((long long)m) - 1;
    float wx = __int_as_float(__builtin_amdgcn_readlane(__float_as_int(sx), L));
    float wy = __int_as_float(__builtin_amdgcn_readlane(__float_as_int(sy), L));
    float wz = __int_as_float(__builtin_amdgcn_readlane(__float_as_int(sz), L));

    const int slot = it & 1;
    if (lane == 0)
      part[slot][wv] = make_uint4(__float_as_uint(vmax), __float_as_uint(wx),
                                  __float_as_uint(wy), __float_as_uint(wz));
    __syncthreads();   // the ONLY barrier; ping-pong makes it WAR-safe

    // 8-slot cross-wave argmax, payload = coords (strict > keeps lowest wave)
    {
      uint4 r0 = part[slot][0];
      float v  = __uint_as_float(r0.x);
      float nx = __uint_as_float(r0.y);
      float ny = __uint_as_float(r0.z);
      float nz = __uint_as_float(r0.w);
      #pragma unroll
      for (int wz2 = 1; wz2 < 8; ++wz2) {
        uint4 rw = part[slot][wz2];
        float vw = __uint_as_float(rw.x);
        bool g = (vw > v);
        v  = g ? vw : v;
        nx = g ? __uint_as_float(rw.y) : nx;
        ny = g ? __uint_as_float(rw.z) : ny;
        nz = g ? __uint_as_float(rw.w) : nz;
      }
      cx = nx; cy = ny; cz = nz;
    }
  }

  __syncthreads();
  float* ob = out_sampled + (size_t)b * NSAMP * 3;
  for (int i = t; i < NSAMP * 3; i += 512) ob[i] = out_lds[i];
}

// ---------------------------------------------------------------------------
// Kernel 2: query_ball_point — original (bit-exact, DO NOT TOUCH).
// R16 SoA variant regressed (prep overhead; xyz already L2-resident).
// ---------------------------------------------------------------------------
__global__ __launch_bounds__(256) void ball_kernel(
    const float* __restrict__ xyz, const float* __restrict__ sampled,
    int* __restrict__ gidx)
{
  #pragma clang fp contract(off)
  const float R2 = (float)(0.2 * 0.2);
  int gt = blockIdx.x * 256 + threadIdx.x;
  int w = gt >> 6;
  int lane = gt & 63;
  const int b = w >> 10;
  const float* cp = sampled + (size_t)w * 3;
  float cx = cp[0], cy = cp[1], cz = cp[2];
  float na = ((cx * cx) + (cy * cy)) + (cz * cz);   // eager: plain adds
  const float* bx = xyz + (size_t)b * N_PTS * 3;
  int* out = gidx + (size_t)w * NGRP;

  int cnt = 0;
  int first = 0;
  for (int base = 0; base < N_PTS && cnt < NGRP; base += 64) {
    int p = base + lane;
    float x = bx[p * 3 + 0];
    float y = bx[p * 3 + 1];
    float z = bx[p * 3 + 2];
    float nb  = ((x * x) + (y * y)) + (z * z);      // eager: plain adds
    float dot = fmaf(cz, z, fmaf(cy, y, cx * x));   // Eigen fma chain
    float sq  = (na + nb) - (2.0f * dot);
    bool inr = !(sq > R2);
    unsigned long long m = __ballot(inr);
    if (cnt == 0 && m != 0ull) first = base + (__ffsll(m) - 1);
    int before = __popcll(m & ((1ull << lane) - 1ull));
    int pos = cnt + before;
    if (inr && pos < NGRP) out[pos] = p;
    cnt += __popcll(m);
  }
  if (cnt < NGRP) {
    int q = cnt + lane;
    if (q < NGRP) out[q] = first;
  }
}

// ---------------------------------------------------------------------------
// Kernel 2.5: weight prep — pack W1/W2/W3 into fragment-ordered bf16 records.
// Record (nt, ks) holds the B-fragment for one 16-col tile / one K-step:
//   record[lane][j] = W[k = 32ks + (lane>>4)*8 + j][n = 16nt + (lane&15)]
// (zero-padded k >= K). 1KB/record, lane*16B consecutive -> coalesced loads.
// Layers: L1 4nt x 3ks = 12 recs, L2 8x2 = 16, L3 16x4 = 64. Total 92KB.
// L1 uses PERMUTED feature order (fea at k'=0..63, rel at k'=64..66,
// pad 67..95); W1 rows permuted to match (k'<64 -> row k'+3; 64..66 -> k'-64).
// ---------------------------------------------------------------------------
__global__ __launch_bounds__(256) void prep_w_kernel(
    const float* __restrict__ W1, const float* __restrict__ W2,
    const float* __restrict__ W3, unsigned short* __restrict__ wf1,
    unsigned short* __restrict__ wf2, unsigned short* __restrict__ wf3)
{
  int tid = blockIdx.x * 256 + threadIdx.x;
  int rec = tid >> 6, lane = tid & 63;
  if (rec >= 92) return;
  const float* W; unsigned short* dst; int N, K, ksteps, rl; int permuted;
  if (rec < 12)      { W = W1; dst = wf1; N = 64;  K = 67;  ksteps = 3; rl = rec;     permuted = 1; }
  else if (rec < 28) { W = W2; dst = wf2; N = 128; K = 64;  ksteps = 2; rl = rec - 12; permuted = 0; }
  else               { W = W3; dst = wf3; N = 256; K = 128; ksteps = 4; rl = rec - 28; permuted = 0; }
  int nt = rl / ksteps, ks = rl - nt * ksteps;
  int n  = nt * 16 + (lane & 15);
  int kb = ks * 32 + (lane >> 4) * 8;
  unsigned short v[8] __attribute__((aligned(16)));
  #pragma unroll
  for (int j = 0; j < 8; ++j) {
    int k = kb + j;
    float val;
    if (permuted) {
      if (k < 64)      val = W[(k + 3) * N + n];   // fea weight rows
      else if (k < K)  val = W[(k - 64) * N + n];  // rel weight rows (k=64..66)
      else             val = 0.0f;
    } else {
      val = (k < K) ? W[k * N + n] : 0.0f;
    }
    v[j] = f2bf(val);
  }
  *(uint4*)(dst + ((size_t)rl * 64 + lane) * 8) = *(const uint4*)v;
}

// ---------------------------------------------------------------------------
// Kernel 3: gather + MLP via bf16 MFMA (fp32 accumulate) + max-pool.
// R15 config (empirical optimum; R16's M=128 halved occupancy and regressed):
// TWO centroids per block (M=64 rows), 8192 blocks, 4 blocks/CU.
//  - nt-major wave tiling: B-frag loaded once, reused across 4 m-tiles.
//  - pool via register tree + __shfl_xor(16/32).
//  - chunked XCD swizzle (bijective, 8192%8==0).
// Frag layouts (gfx950, HW-verified per guide):
//   A[m=lane&15][k=(lane>>4)*8+j]   B[n=lane&15][k=(lane>>4)*8+j]
//   C/D: col=lane&15, row=(lane>>4)*4+reg
// ---------------------------------------------------------------------------
__global__ __launch_bounds__(256, 4) void mlp_mfma_kernel(
    const float* __restrict__ xyz, const float* __restrict__ fea,
    const float* __restrict__ sampled, const int* __restrict__ gidx,
    const unsigned short* __restrict__ wf1, const unsigned short* __restrict__ wf2,
    const unsigned short* __restrict__ wf3, const float* __restrict__ b1,
    const float* __restrict__ b2, const float* __restrict__ b3,
    float* __restrict__ out)
{
  __shared__ __align__(16) unsigned short fT[64][104];  // feats bf16, K=96 pad
  __shared__ __align__(16) unsigned short h1[64][72];   // K=64 (+8 bank pad)
  __shared__ __align__(16) unsigned short h2[64][136];  // K=128 (+8 bank pad)
  __shared__ int   sidx[64];
  __shared__ float sc[8];

  // chunked XCD swizzle: 8192 blocks -> 1024 consecutive work items per XCD
  const int wk  = (blockIdx.x & 7) * 1024 + (blockIdx.x >> 3);
  const int bs0 = wk * 2;            // first of two centroids (same batch)
  const int b   = bs0 >> 10;
  const int t   = threadIdx.x;
  const int w    = t >> 6;
  const int lane = t & 63;
  const int quad = lane >> 4;
  const int ncol = lane & 15;

  if (t < 64) sidx[t] = gidx[(size_t)bs0 * 32 + t];
  if (t < 6)  sc[t] = sampled[(size_t)bs0 * 3 + t];
  __syncthreads();

  // gather (permuted layout): fea -> cols 0..63 via 4 coalesced float4 loads
  // per thread (4 threads per point); rel -> cols 64..66; zeros 67..95.
  {
    const int pt = t >> 2, c0 = t & 3;
    const int p = sidx[pt];
    const float4* fp4 = (const float4*)(fea + ((size_t)b * N_PTS + p) * 64);
    #pragma unroll
    for (int j = 0; j < 4; ++j) {
      float4 fv = fp4[c0 + 4 * j];
      unsigned short s4[4] __attribute__((aligned(8)));
      s4[0] = f2bf(fv.x); s4[1] = f2bf(fv.y);
      s4[2] = f2bf(fv.z); s4[3] = f2bf(fv.w);
      *(uint2*)&fT[pt][(c0 + 4 * j) * 4] = *(const uint2*)s4;
    }
    if (c0 == 0) {
      const float* xp = xyz + ((size_t)b * N_PTS + p) * 3;
      const int cc = (pt >> 5) * 3;
      unsigned short sr[4] __attribute__((aligned(8)));
      sr[0] = f2bf(xp[0] - sc[cc + 0]);
      sr[1] = f2bf(xp[1] - sc[cc + 1]);
      sr[2] = f2bf(xp[2] - sc[cc + 2]);
      sr[3] = 0;
      *(uint2*)&fT[pt][64] = *(const uint2*)sr;
      *(uint2*)&fT[pt][68] = (uint2){0u, 0u};
    } else {
      // zeros: c0=1 -> 72..79, c0=2 -> 80..87, c0=3 -> 88..95
      *(uint4*)&fT[pt][72 + (c0 - 1) * 8] = (uint4){0u, 0u, 0u, 0u};
    }
  }
  __syncthreads();

  // layer 1: out [64 x 64]. wave w owns nt=w; B loaded once per ks, reused
  // across 4 m-tiles. K: 3 steps.
  {
    const int nt = w;
    float bb = b1[nt * 16 + ncol];
    f32x4 acc[4];
    #pragma unroll
    for (int mt = 0; mt < 4; ++mt) acc[mt] = (f32x4){bb, bb, bb, bb};
    #pragma unroll
    for (int ks = 0; ks < 3; ++ks) {
      bf16x8 bf = *(const bf16x8*)(wf1 + ((size_t)(nt * 3 + ks) * 64 + lane) * 8);
      #pragma unroll
      for (int mt = 0; mt < 4; ++mt) {
        bf16x8 a = *(const bf16x8*)&fT[mt * 16 + ncol][ks * 32 + quad * 8];
        acc[mt] = __builtin_amdgcn_mfma_f32_16x16x32_bf16(a, bf, acc[mt], 0, 0, 0);
      }
    }
    #pragma unroll
    for (int mt = 0; mt < 4; ++mt)
      #pragma unroll
      for (int r = 0; r < 4; ++r)
        h1[mt * 16 + quad * 4 + r][nt * 16 + ncol] = f2bf(fmaxf(acc[mt][r], 0.0f));
  }
  __syncthreads();

  // layer 2: out [64 x 128]. wave w owns nt in {2w, 2w+1}. K: 2 steps.
  #pragma unroll
  for (int i = 0; i < 2; ++i) {
    const int nt = 2 * w + i;
    float bb = b2[nt * 16 + ncol];
    f32x4 acc[4];
    #pragma unroll
    for (int mt = 0; mt < 4; ++mt) acc[mt] = (f32x4){bb, bb, bb, bb};
    #pragma unroll
    for (int ks = 0; ks < 2; ++ks) {
      bf16x8 bf = *(const bf16x8*)(wf2 + ((size_t)(nt * 2 + ks) * 64 + lane) * 8);
      #pragma unroll
      for (int mt = 0; mt < 4; ++mt) {
        bf16x8 a = *(const bf16x8*)&h1[mt * 16 + ncol][ks * 32 + quad * 8];
        acc[mt] = __builtin_amdgcn_mfma_f32_16x16x32_bf16(a, bf, acc[mt], 0, 0, 0);
      }
    }
    #pragma unroll
    for (int mt = 0; mt < 4; ++mt)
      #pragma unroll
      for (int r = 0; r < 4; ++r)
        h2[mt * 16 + quad * 4 + r][nt * 16 + ncol] = f2bf(fmaxf(acc[mt][r], 0.0f));
  }
  __syncthreads();

  // layer 3 + pool: out [64 x 256]. wave w owns nt in {4w..4w+3}, processed
  // in 2 halves (VGPR cap 128 at waves_per_eu=4). K: 4 steps, ks-outer with
  // hoisted A-frags. Pool: reg tree over (mt,r) + shfl_xor(16/32) over quads.
  #pragma unroll
  for (int half = 0; half < 2; ++half) {
    f32x4 acc[2][4];     // [nt_i][mt]
    #pragma unroll
    for (int i = 0; i < 2; ++i) {
      const int nt = 4 * w + half * 2 + i;
      float bb = b3[nt * 16 + ncol];
      #pragma unroll
      for (int mt = 0; mt < 4; ++mt) acc[i][mt] = (f32x4){bb, bb, bb, bb};
    }
    #pragma unroll
    for (int ks = 0; ks < 4; ++ks) {
      bf16x8 a[4];
      #pragma unroll
      for (int mt = 0; mt < 4; ++mt)
        a[mt] = *(const bf16x8*)&h2[mt * 16 + ncol][ks * 32 + quad * 8];
      #pragma unroll
      for (int i = 0; i < 2; ++i) {
        const int nt = 4 * w + half * 2 + i;
        bf16x8 bf = *(const bf16x8*)(wf3 + ((size_t)(nt * 4 + ks) * 64 + lane) * 8);
        #pragma unroll
        for (int mt = 0; mt < 4; ++mt)
          acc[i][mt] = __builtin_amdgcn_mfma_f32_16x16x32_bf16(a[mt], bf, acc[i][mt], 0, 0, 0);
      }
    }
    #pragma unroll
    for (int i = 0; i < 2; ++i) {
      const int nt = 4 * w + half * 2 + i;
      // centroid 0 = rows 0..31 (mt 0,1); centroid 1 = rows 32..63 (mt 2,3)
      float m0 = fmaxf(fmaxf(acc[i][0][0], acc[i][0][1]),
                       fmaxf(acc[i][0][2], acc[i][0][3]));
      m0 = fmaxf(m0, fmaxf(fmaxf(acc[i][1][0], acc[i][1][1]),
                           fmaxf(acc[i][1][2], acc[i][1][3])));
      float m1 = fmaxf(fmaxf(acc[i][2][0], acc[i][2][1]),
                       fmaxf(acc[i][2][2], acc[i][2][3]));
      m1 = fmaxf(m1, fmaxf(fmaxf(acc[i][3][0], acc[i][3][1]),
                           fmaxf(acc[i][3][2], acc[i][3][3])));
      m0 = fmaxf(m0, __shfl_xor(m0, 16));
      m0 = fmaxf(m0, __shfl_xor(m0, 32));
      m1 = fmaxf(m1, __shfl_xor(m1, 16));
      m1 = fmaxf(m1, __shfl_xor(m1, 32));
      if (quad == 0)
        out[(size_t)bs0 * 256 + nt * 16 + ncol] = fmaxf(m0, 0.0f);
      else if (quad == 1)
        out[(size_t)(bs0 + 1) * 256 + nt * 16 + ncol] = fmaxf(m1, 0.0f);
    }
  }
}

// ---------------------------------------------------------------------------
extern "C" void kernel_launch(void* const* d_in, const int* in_sizes, int n_in,
                              void* d_out, int out_size, void* d_ws, size_t ws_size,
                              hipStream_t stream) {
  const float* xyz = (const float*)d_in[0];
  const float* fea = (const float*)d_in[1];
  const float* W1  = (const float*)d_in[2];
  const float* b1  = (const float*)d_in[3];
  const float* W2  = (const float*)d_in[4];
  const float* b2  = (const float*)d_in[5];
  const float* W3  = (const float*)d_in[6];
  const float* b3  = (const float*)d_in[7];

  float* outp    = (float*)d_out;
  float* sampled = outp;                    // output 0: (16,1024,3)
  float* mlp_out = outp + 16 * 1024 * 3;    // output 1: (16,1024,256)
  int*   gidx    = (int*)d_ws;              // 2 MB
  unsigned short* wf1 = (unsigned short*)((char*)d_ws + (2u << 20));
  unsigned short* wf2 = wf1 + (size_t)12 * 64 * 8;   // 12 KB after wf1
  unsigned short* wf3 = wf2 + (size_t)16 * 64 * 8;   // 16 KB after wf2

  fps_kernel<<<16, 512, 0, stream>>>(xyz, sampled);
  prep_w_kernel<<<23, 256, 0, stream>>>(W1, W2, W3, wf1, wf2, wf3);
  ball_kernel<<<4096, 256, 0, stream>>>(xyz, sampled, gidx);
  mlp_mfma_kernel<<<8192, 256, 0, stream>>>(xyz, fea, sampled, gidx,
                                            wf1, wf2, wf3, b1, b2, b3, mlp_out);
}

// Round 8
// 1012.394 us; speedup vs baseline: 1.1698x; 1.1698x over previous
//
#include <hip/hip_runtime.h>
#include <hip/hip_bf16.h>

#define N_PTS 8192
#define NSAMP 1024
#define NGRP  32

typedef __attribute__((ext_vector_type(8))) short bf16x8;   // MFMA A/B frag
typedef __attribute__((ext_vector_type(4))) float f32x4;    // MFMA C/D frag
typedef __attribute__((ext_vector_type(2))) float f32x2;    // packed fp32 pair

static __device__ inline unsigned short f2bf(float f) {
  __hip_bfloat16 h = __float2bfloat16(f);   // RTNE
  return __builtin_bit_cast(unsigned short, h);
}

// DPP max step: invalid lanes keep 'old' (=r), identity for max.
#define DPP_MAXSTEP(r, ctrl)                                                  \
  r = fmaxf(r, __int_as_float(__builtin_amdgcn_update_dpp(                    \
          __float_as_int(r), __float_as_int(r), (ctrl), 0xf, 0xf, false)))

// 8-slot cross-wave argmax from LDS (strict > keeps lowest wave on ties).
#define FINAL8(P, V, F) do {                                                  \
    const uint4* pp_ = (const uint4*)&(P)[0];                                 \
    uint4 p0_ = pp_[0], p1_ = pp_[1], p2_ = pp_[2], p3_ = pp_[3];             \
    V = __uint_as_float(p0_.x); F = p0_.y;                                    \
    float q_;                                                                 \
    q_ = __uint_as_float(p0_.z); if (q_ > V) { V = q_; F = p0_.w; }           \
    q_ = __uint_as_float(p1_.x); if (q_ > V) { V = q_; F = p1_.y; }           \
    q_ = __uint_as_float(p1_.z); if (q_ > V) { V = q_; F = p1_.w; }           \
    q_ = __uint_as_float(p2_.x); if (q_ > V) { V = q_; F = p2_.y; }           \
    q_ = __uint_as_float(p2_.z); if (q_ > V) { V = q_; F = p2_.w; }           \
    q_ = __uint_as_float(p3_.x); if (q_ > V) { V = q_; F = p3_.y; }           \
    q_ = __uint_as_float(p3_.z); if (q_ > V) { V = q_; F = p3_.w; }           \
  } while (0)

static __device__ inline void load16(const float* __restrict__ bx, int t,
                                     float px[16], float py[16], float pz[16]) {
  const float4* src = (const float4*)(bx + t * 48);
  float4 v0 = src[0], v1 = src[1], v2 = src[2];
  float4 v3 = src[3], v4 = src[4], v5 = src[5];
  float4 v6 = src[6], v7 = src[7], v8 = src[8];
  float4 v9 = src[9], v10 = src[10], v11 = src[11];
  px[ 0]=v0.x; py[ 0]=v0.y; pz[ 0]=v0.z;
  px[ 1]=v0.w; py[ 1]=v1.x; pz[ 1]=v1.y;
  px[ 2]=v1.z; py[ 2]=v1.w; pz[ 2]=v2.x;
  px[ 3]=v2.y; py[ 3]=v2.z; pz[ 3]=v2.w;
  px[ 4]=v3.x; py[ 4]=v3.y; pz[ 4]=v3.z;
  px[ 5]=v3.w; py[ 5]=v4.x; pz[ 5]=v4.y;
  px[ 6]=v4.z; py[ 6]=v4.w; pz[ 6]=v5.x;
  px[ 7]=v5.y; py[ 7]=v5.z; pz[ 7]=v5.w;
  px[ 8]=v6.x; py[ 8]=v6.y; pz[ 8]=v6.z;
  px[ 9]=v6.w; py[ 9]=v7.x; pz[ 9]=v7.y;
  px[10]=v7.z; py[10]=v7.w; pz[10]=v8.x;
  px[11]=v8.y; py[11]=v8.z; pz[11]=v8.w;
  px[12]=v9.x; py[12]=v9.y; pz[12]=v9.z;
  px[13]=v9.w; py[13]=v10.x; pz[13]=v10.y;
  px[14]=v10.z; py[14]=v10.w; pz[14]=v11.x;
  px[15]=v11.y; py[15]=v11.z; pz[15]=v11.w;
}

// ---------------------------------------------------------------------------
// Kernel 1: FUSED fps + weight-prep.
// Blocks 0..15: farthest point sampling — R12 internals, byte-identical
// (empirical optimum 821us; R11/R13/R17 all regressed — fps is FROZEN).
// Blocks 16..27: weight packing (independent of fps; runs on idle CUs in
// fps's 822us shadow, removing its serial dispatch+exec time).
//
// fps notes: wall pinned ~1900-2000 cy/iter across 4 structural variants;
// serial chain (dist dep -> DPP -> ballot -> LDS write -> barrier -> FINAL8
// -> dependent centroid ds_read) dominates; issue slack exists only ACROSS
// waves, never inside the lockstep serial segment (R17 lesson).
//   d = fma(dz,dz, fma(dy,dy, dx*dx))          (bit-exact, DO NOT TOUCH)
// argmax ties -> lowest index.
//
// prep_w notes: record (nt,ks) = B-fragment for one 16-col tile / K-step:
//   record[lane][j] = W[k = 32ks + (lane>>4)*8 + j][n = 16nt + (lane&15)]
// L1 rows PERMUTED (fea k'=0..63 -> W1 row k'+3; rel k'=64..66 -> row k'-64)
// to match the mlp's vectorized gather layout. L1 12 recs, L2 16, L3 64.
// ---------------------------------------------------------------------------
__global__
__attribute__((amdgpu_flat_work_group_size(512, 512)))
__attribute__((amdgpu_waves_per_eu(2, 2)))
void fps_prep_kernel(
    const float* __restrict__ xyz, float* __restrict__ out_sampled,
    const float* __restrict__ W1, const float* __restrict__ W2,
    const float* __restrict__ W3, unsigned short* __restrict__ wf1,
    unsigned short* __restrict__ wf2, unsigned short* __restrict__ wf3)
{
  #pragma clang fp contract(off)
  const int t = threadIdx.x;

  if (blockIdx.x >= 16) {
    // ---------------- weight-prep path (blocks 16..27) ----------------
    int tid = (blockIdx.x - 16) * 512 + t;
    int rec = tid >> 6, lane = tid & 63;
    if (rec >= 92) return;
    const float* W; unsigned short* dst; int N, K, ksteps, rl; int permuted;
    if (rec < 12)      { W = W1; dst = wf1; N = 64;  K = 67;  ksteps = 3; rl = rec;      permuted = 1; }
    else if (rec < 28) { W = W2; dst = wf2; N = 128; K = 64;  ksteps = 2; rl = rec - 12; permuted = 0; }
    else               { W = W3; dst = wf3; N = 256; K = 128; ksteps = 4; rl = rec - 28; permuted = 0; }
    int nt = rl / ksteps, ks = rl - nt * ksteps;
    int n  = nt * 16 + (lane & 15);
    int kb = ks * 32 + (lane >> 4) * 8;
    unsigned short v[8] __attribute__((aligned(16)));
    #pragma unroll
    for (int j = 0; j < 8; ++j) {
      int k = kb + j;
      float val;
      if (permuted) {
        if (k < 64)      val = W[(k + 3) * N + n];   // fea weight rows
        else if (k < K)  val = W[(k - 64) * N + n];  // rel rows (k=64..66)
        else             val = 0.0f;
      } else {
        val = (k < K) ? W[k * N + n] : 0.0f;
      }
      v[j] = f2bf(val);
    }
    *(uint4*)(dst + ((size_t)rl * 64 + lane) * 8) = *(const uint4*)v;
    return;
  }

  // ---------------------- fps path (blocks 0..15) ----------------------
  const int b = blockIdx.x;
  const float* bx = xyz + (size_t)b * N_PTS * 3;

  float px[16], py[16], pz[16];
  load16(bx, t, px, py, pz);

  f32x2 px2[8], py2[8], pz2[8], ds2[8];
  #pragma unroll
  for (int j = 0; j < 8; ++j) {
    px2[j] = (f32x2){px[2*j], px[2*j+1]};
    py2[j] = (f32x2){py[2*j], py[2*j+1]};
    pz2[j] = (f32x2){pz[2*j], pz[2*j+1]};
    ds2[j] = (f32x2){10000000000.0f, 10000000000.0f};
  }

  __shared__ float lds_p[N_PTS * 3];    // full point table (96 KB): centroid
  __shared__ float out_lds[NSAMP * 3];  // centroids, flushed at end
  __shared__ __align__(16) uint2 part[2][8];  // ping-pong (value bits, index)

  // one-time coalesced stage of the point table (visible at first barrier)
  for (int i = t; i < N_PTS * 3; i += 512) lds_p[i] = bx[i];

  const int lane = t & 63;
  const int wv   = t >> 6;

  float cx = bx[0], cy = bx[1], cz = bx[2];  // initial centroid = point 0

  for (int it = 0; it < NSAMP; ++it) {
    if (t == 0) {
      out_lds[it * 3 + 0] = cx;
      out_lds[it * 3 + 1] = cy;
      out_lds[it * 3 + 2] = cz;
    }

    const f32x2 c2x = (f32x2){cx, cx};
    const f32x2 c2y = (f32x2){cy, cy};
    const f32x2 c2z = (f32x2){cz, cz};
    f32x2 bv2 = (f32x2){-1.0f, -1.0f};
    #pragma unroll
    for (int j = 0; j < 8; ++j) {
      f32x2 dx = px2[j] - c2x;
      f32x2 dy = py2[j] - c2y;
      f32x2 dz = pz2[j] - c2z;
      f32x2 d  = __builtin_elementwise_fma(
          dz, dz, __builtin_elementwise_fma(dy, dy, dx * dx));  // scan-fused
      f32x2 nd = __builtin_elementwise_min(ds2[j], d);
      ds2[j] = nd;
      bv2 = __builtin_elementwise_max(bv2, nd);
    }
    float bv = fmaxf(bv2.x, bv2.y);   // min/max reassociation is exact

    int bi = t * 16 + 15;
    #pragma unroll
    for (int r = 14; r >= 0; --r) {
      float dr = (r & 1) ? ds2[r >> 1].y : ds2[r >> 1].x;
      bi = (dr == bv) ? (t * 16 + r) : bi;
    }

    float rmax = bv;
    DPP_MAXSTEP(rmax, 0x111);  // row_shr:1
    DPP_MAXSTEP(rmax, 0x112);  // row_shr:2
    DPP_MAXSTEP(rmax, 0x114);  // row_shr:4
    DPP_MAXSTEP(rmax, 0x118);  // row_shr:8
    DPP_MAXSTEP(rmax, 0x142);  // row_bcast:15
    DPP_MAXSTEP(rmax, 0x143);  // row_bcast:31
    float vmax = __int_as_float(
        __builtin_amdgcn_readlane(__float_as_int(rmax), 63));

    unsigned long long m = __ballot(bv == vmax);
    int L = __ffsll((long long)m) - 1;
    int widx = __builtin_amdgcn_readlane(bi, L);

    const int slot = it & 1;
    if (lane == 0) part[slot][wv] = make_uint2(__float_as_uint(vmax), (unsigned)widx);
    __syncthreads();   // the ONLY barrier; ping-pong makes it WAR-safe

    float v; unsigned f;
    FINAL8(part[slot], v, f);

    cx = lds_p[f * 3 + 0];   // broadcast ds_read (beats global L2 ~200cy)
    cy = lds_p[f * 3 + 1];
    cz = lds_p[f * 3 + 2];
  }

  __syncthreads();
  float* ob = out_sampled + (size_t)b * NSAMP * 3;
  for (int i = t; i < NSAMP * 3; i += 512) ob[i] = out_lds[i];
}

// ---------------------------------------------------------------------------
// Kernel 2: query_ball_point — original (bit-exact, DO NOT TOUCH).
// ---------------------------------------------------------------------------
__global__ __launch_bounds__(256) void ball_kernel(
    const float* __restrict__ xyz, const float* __restrict__ sampled,
    int* __restrict__ gidx)
{
  #pragma clang fp contract(off)
  const float R2 = (float)(0.2 * 0.2);
  int gt = blockIdx.x * 256 + threadIdx.x;
  int w = gt >> 6;
  int lane = gt & 63;
  const int b = w >> 10;
  const float* cp = sampled + (size_t)w * 3;
  float cx = cp[0], cy = cp[1], cz = cp[2];
  float na = ((cx * cx) + (cy * cy)) + (cz * cz);   // eager: plain adds
  const float* bx = xyz + (size_t)b * N_PTS * 3;
  int* out = gidx + (size_t)w * NGRP;

  int cnt = 0;
  int first = 0;
  for (int base = 0; base < N_PTS && cnt < NGRP; base += 64) {
    int p = base + lane;
    float x = bx[p * 3 + 0];
    float y = bx[p * 3 + 1];
    float z = bx[p * 3 + 2];
    float nb  = ((x * x) + (y * y)) + (z * z);      // eager: plain adds
    float dot = fmaf(cz, z, fmaf(cy, y, cx * x));   // Eigen fma chain
    float sq  = (na + nb) - (2.0f * dot);
    bool inr = !(sq > R2);
    unsigned long long m = __ballot(inr);
    if (cnt == 0 && m != 0ull) first = base + (__ffsll(m) - 1);
    int before = __popcll(m & ((1ull << lane) - 1ull));
    int pos = cnt + before;
    if (inr && pos < NGRP) out[pos] = p;
    cnt += __popcll(m);
  }
  if (cnt < NGRP) {
    int q = cnt + lane;
    if (q < NGRP) out[q] = first;
  }
}

// ---------------------------------------------------------------------------
// Kernel 3: gather + MLP via bf16 MFMA (fp32 accumulate) + max-pool.
// R15 config, byte-identical (empirical optimum; M=128 regressed in R16):
// TWO centroids per block (M=64 rows), 8192 blocks, 4 blocks/CU.
//  - nt-major wave tiling: B-frag loaded once, reused across 4 m-tiles.
//  - pool via register tree + __shfl_xor(16/32).
//  - chunked XCD swizzle (bijective, 8192%8==0).
// Frag layouts (gfx950, HW-verified per guide):
//   A[m=lane&15][k=(lane>>4)*8+j]   B[n=lane&15][k=(lane>>4)*8+j]
//   C/D: col=lane&15, row=(lane>>4)*4+reg
// ---------------------------------------------------------------------------
__global__ __launch_bounds__(256, 4) void mlp_mfma_kernel(
    const float* __restrict__ xyz, const float* __restrict__ fea,
    const float* __restrict__ sampled, const int* __restrict__ gidx,
    const unsigned short* __restrict__ wf1, const unsigned short* __restrict__ wf2,
    const unsigned short* __restrict__ wf3, const float* __restrict__ b1,
    const float* __restrict__ b2, const float* __restrict__ b3,
    float* __restrict__ out)
{
  __shared__ __align__(16) unsigned short fT[64][104];  // feats bf16, K=96 pad
  __shared__ __align__(16) unsigned short h1[64][72];   // K=64 (+8 bank pad)
  __shared__ __align__(16) unsigned short h2[64][136];  // K=128 (+8 bank pad)
  __shared__ int   sidx[64];
  __shared__ float sc[8];

  // chunked XCD swizzle: 8192 blocks -> 1024 consecutive work items per XCD
  const int wk  = (blockIdx.x & 7) * 1024 + (blockIdx.x >> 3);
  const int bs0 = wk * 2;            // first of two centroids (same batch)
  const int b   = bs0 >> 10;
  const int t   = threadIdx.x;
  const int w    = t >> 6;
  const int lane = t & 63;
  const int quad = lane >> 4;
  const int ncol = lane & 15;

  if (t < 64) sidx[t] = gidx[(size_t)bs0 * 32 + t];
  if (t < 6)  sc[t] = sampled[(size_t)bs0 * 3 + t];
  __syncthreads();

  // gather (permuted layout): fea -> cols 0..63 via 4 coalesced float4 loads
  // per thread (4 threads per point); rel -> cols 64..66; zeros 67..95.
  {
    const int pt = t >> 2, c0 = t & 3;
    const int p = sidx[pt];
    const float4* fp4 = (const float4*)(fea + ((size_t)b * N_PTS + p) * 64);
    #pragma unroll
    for (int j = 0; j < 4; ++j) {
      float4 fv = fp4[c0 + 4 * j];
      unsigned short s4[4] __attribute__((aligned(8)));
      s4[0] = f2bf(fv.x); s4[1] = f2bf(fv.y);
      s4[2] = f2bf(fv.z); s4[3] = f2bf(fv.w);
      *(uint2*)&fT[pt][(c0 + 4 * j) * 4] = *(const uint2*)s4;
    }
    if (c0 == 0) {
      const float* xp = xyz + ((size_t)b * N_PTS + p) * 3;
      const int cc = (pt >> 5) * 3;
      unsigned short sr[4] __attribute__((aligned(8)));
      sr[0] = f2bf(xp[0] - sc[cc + 0]);
      sr[1] = f2bf(xp[1] - sc[cc + 1]);
      sr[2] = f2bf(xp[2] - sc[cc + 2]);
      sr[3] = 0;
      *(uint2*)&fT[pt][64] = *(const uint2*)sr;
      *(uint2*)&fT[pt][68] = (uint2){0u, 0u};
    } else {
      // zeros: c0=1 -> 72..79, c0=2 -> 80..87, c0=3 -> 88..95
      *(uint4*)&fT[pt][72 + (c0 - 1) * 8] = (uint4){0u, 0u, 0u, 0u};
    }
  }
  __syncthreads();

  // layer 1: out [64 x 64]. wave w owns nt=w; B loaded once per ks, reused
  // across 4 m-tiles. K: 3 steps.
  {
    const int nt = w;
    float bb = b1[nt * 16 + ncol];
    f32x4 acc[4];
    #pragma unroll
    for (int mt = 0; mt < 4; ++mt) acc[mt] = (f32x4){bb, bb, bb, bb};
    #pragma unroll
    for (int ks = 0; ks < 3; ++ks) {
      bf16x8 bf = *(const bf16x8*)(wf1 + ((size_t)(nt * 3 + ks) * 64 + lane) * 8);
      #pragma unroll
      for (int mt = 0; mt < 4; ++mt) {
        bf16x8 a = *(const bf16x8*)&fT[mt * 16 + ncol][ks * 32 + quad * 8];
        acc[mt] = __builtin_amdgcn_mfma_f32_16x16x32_bf16(a, bf, acc[mt], 0, 0, 0);
      }
    }
    #pragma unroll
    for (int mt = 0; mt < 4; ++mt)
      #pragma unroll
      for (int r = 0; r < 4; ++r)
        h1[mt * 16 + quad * 4 + r][nt * 16 + ncol] = f2bf(fmaxf(acc[mt][r], 0.0f));
  }
  __syncthreads();

  // layer 2: out [64 x 128]. wave w owns nt in {2w, 2w+1}. K: 2 steps.
  #pragma unroll
  for (int i = 0; i < 2; ++i) {
    const int nt = 2 * w + i;
    float bb = b2[nt * 16 + ncol];
    f32x4 acc[4];
    #pragma unroll
    for (int mt = 0; mt < 4; ++mt) acc[mt] = (f32x4){bb, bb, bb, bb};
    #pragma unroll
    for (int ks = 0; ks < 2; ++ks) {
      bf16x8 bf = *(const bf16x8*)(wf2 + ((size_t)(nt * 2 + ks) * 64 + lane) * 8);
      #pragma unroll
      for (int mt = 0; mt < 4; ++mt) {
        bf16x8 a = *(const bf16x8*)&h1[mt * 16 + ncol][ks * 32 + quad * 8];
        acc[mt] = __builtin_amdgcn_mfma_f32_16x16x32_bf16(a, bf, acc[mt], 0, 0, 0);
      }
    }
    #pragma unroll
    for (int mt = 0; mt < 4; ++mt)
      #pragma unroll
      for (int r = 0; r < 4; ++r)
        h2[mt * 16 + quad * 4 + r][nt * 16 + ncol] = f2bf(fmaxf(acc[mt][r], 0.0f));
  }
  __syncthreads();

  // layer 3 + pool: out [64 x 256]. wave w owns nt in {4w..4w+3}, processed
  // in 2 halves (VGPR cap 128 at waves_per_eu=4). K: 4 steps, ks-outer with
  // hoisted A-frags. Pool: reg tree over (mt,r) + shfl_xor(16/32) over quads.
  #pragma unroll
  for (int half = 0; half < 2; ++half) {
    f32x4 acc[2][4];     // [nt_i][mt]
    #pragma unroll
    for (int i = 0; i < 2; ++i) {
      const int nt = 4 * w + half * 2 + i;
      float bb = b3[nt * 16 + ncol];
      #pragma unroll
      for (int mt = 0; mt < 4; ++mt) acc[i][mt] = (f32x4){bb, bb, bb, bb};
    }
    #pragma unroll
    for (int ks = 0; ks < 4; ++ks) {
      bf16x8 a[4];
      #pragma unroll
      for (int mt = 0; mt < 4; ++mt)
        a[mt] = *(const bf16x8*)&h2[mt * 16 + ncol][ks * 32 + quad * 8];
      #pragma unroll
      for (int i = 0; i < 2; ++i) {
        const int nt = 4 * w + half * 2 + i;
        bf16x8 bf = *(const bf16x8*)(wf3 + ((size_t)(nt * 4 + ks) * 64 + lane) * 8);
        #pragma unroll
        for (int mt = 0; mt < 4; ++mt)
          acc[i][mt] = __builtin_amdgcn_mfma_f32_16x16x32_bf16(a[mt], bf, acc[i][mt], 0, 0, 0);
      }
    }
    #pragma unroll
    for (int i = 0; i < 2; ++i) {
      const int nt = 4 * w + half * 2 + i;
      // centroid 0 = rows 0..31 (mt 0,1); centroid 1 = rows 32..63 (mt 2,3)
      float m0 = fmaxf(fmaxf(acc[i][0][0], acc[i][0][1]),
                       fmaxf(acc[i][0][2], acc[i][0][3]));
      m0 = fmaxf(m0, fmaxf(fmaxf(acc[i][1][0], acc[i][1][1]),
                           fmaxf(acc[i][1][2], acc[i][1][3])));
      float m1 = fmaxf(fmaxf(acc[i][2][0], acc[i][2][1]),
                       fmaxf(acc[i][2][2], acc[i][2][3]));
      m1 = fmaxf(m1, fmaxf(fmaxf(acc[i][3][0], acc[i][3][1]),
                           fmaxf(acc[i][3][2], acc[i][3][3])));
      m0 = fmaxf(m0, __shfl_xor(m0, 16));
      m0 = fmaxf(m0, __shfl_xor(m0, 32));
      m1 = fmaxf(m1, __shfl_xor(m1, 16));
      m1 = fmaxf(m1, __shfl_xor(m1, 32));
      if (quad == 0)
        out[(size_t)bs0 * 256 + nt * 16 + ncol] = fmaxf(m0, 0.0f);
      else if (quad == 1)
        out[(size_t)(bs0 + 1) * 256 + nt * 16 + ncol] = fmaxf(m1, 0.0f);
    }
  }
}

// ---------------------------------------------------------------------------
extern "C" void kernel_launch(void* const* d_in, const int* in_sizes, int n_in,
                              void* d_out, int out_size, void* d_ws, size_t ws_size,
                              hipStream_t stream) {
  const float* xyz = (const float*)d_in[0];
  const float* fea = (const float*)d_in[1];
  const float* W1  = (const float*)d_in[2];
  const float* b1  = (const float*)d_in[3];
  const float* W2  = (const float*)d_in[4];
  const float* b2  = (const float*)d_in[5];
  const float* W3  = (const float*)d_in[6];
  const float* b3  = (const float*)d_in[7];

  float* outp    = (float*)d_out;
  float* sampled = outp;                    // output 0: (16,1024,3)
  float* mlp_out = outp + 16 * 1024 * 3;    // output 1: (16,1024,256)
  int*   gidx    = (int*)d_ws;              // 2 MB
  unsigned short* wf1 = (unsigned short*)((char*)d_ws + (2u << 20));
  unsigned short* wf2 = wf1 + (size_t)12 * 64 * 8;   // 12 KB after wf1
  unsigned short* wf3 = wf2 + (size_t)16 * 64 * 8;   // 16 KB after wf2

  // fused: blocks 0..15 fps, blocks 16..27 weight prep (idle-CU shadow work)
  fps_prep_kernel<<<28, 512, 0, stream>>>(xyz, sampled, W1, W2, W3,
                                          wf1, wf2, wf3);
  ball_kernel<<<4096, 256, 0, stream>>>(xyz, sampled, gidx);
  mlp_mfma_kernel<<<8192, 256, 0, stream>>>(xyz, fea, sampled, gidx,
                                            wf1, wf2, wf3, b1, b2, b3, mlp_out);
}